// Round 1
// baseline (106.808 us; speedup 1.0000x reference)
//
#include <hip/hip_runtime.h>

#define CINC 64
#define COUT 64
#define HH 32
#define WW 32
#define BB 16

typedef __attribute__((ext_vector_type(8))) short short8;
typedef __attribute__((ext_vector_type(4))) float floatx4;

__device__ __forceinline__ unsigned short f2bf(float f) {
    union { float f; unsigned int u; } c; c.f = f;
    unsigned int r = (c.u + 0x7FFFu + ((c.u >> 16) & 1u)) >> 16;
    return (unsigned short)r;
}

// W3 layout: [tap(9)][s(16)][oc(64)][q(4)][e(8)] bf16
// k = s*32 + q*8 + e (0..511), cin = k/8 = s*4+q, g = k%8 = e
__global__ __launch_bounds__(256) void wt_kernel(const float* __restrict__ sw,
                                                 const float* __restrict__ sc,
                                                 short* __restrict__ W3) {
    int idx = blockIdx.x * blockDim.x + threadIdx.x;
    const int total = 9 * 16 * 64 * 4 * 8;           // 294,912
    if (idx >= total) return;
    int e = idx & 7;
    int q = (idx >> 3) & 3;
    int oc = (idx >> 5) & 63;
    int s = (idx >> 11) & 15;
    int tap = idx >> 15;                              // 0..8
    int cin = s * 4 + q;
    int g = e;
    int kh = tap / 3, kw = tap % 3;
    float w = sw[(((oc * CINC + cin) * 8 + g) * 3 + kh) * 3 + kw] * sc[oc * CINC + cin];
    W3[idx] = (short)f2bf(w);
}

// Fused bases + full-Cin implicit-GEMM conv, direct output write (no partials,
// no reduce pass). Grid: 256 m-blocks (b, row-pair). Block: 8 waves (512 thr),
// 2 waves/SIMD. Wave = (rowl = bit1, xhalf = bit0, ochalf = bit2): mt=1, nt=2
// -> A-reuse 2 (LDS) and B-reuse 2 (L1/L2), same balance as the split kernel.
// LDS: full 64-cin base tile, 4 rows x 34 x 64 x 8g bf16 = 139,264 B (1 blk/CU).
__global__ __launch_bounds__(512, 2) void conv_kernel(const float* __restrict__ xin,
                                                      const short* __restrict__ W3,
                                                      float* __restrict__ out) {
    __shared__ short A[4 * 34 * 512];   // [r(4)][x(34)][slot(64)][e(8)], slot = cin ^ (x&15)

    const int mb = blockIdx.x;
    const int b = mb >> 4;
    const int h0 = (mb & 15) * 2;
    const int t = threadIdx.x;
    const int wave = t >> 6;
    const int lane = t & 63;
    const int l15 = lane & 15;
    const int q = lane >> 4;
    const int xh = (wave & 1) * 16;       // x-half of the row (mt split)
    const int rowl = (wave >> 1) & 1;     // output row within the pair
    const int n0 = (wave >> 2) * 32;      // oc-half

    // ---- prefetch first B fragments (no LDS dependency, overlaps staging) ----
    const short* wp = W3;
    const int boff = (n0 + l15) * 32 + q * 8;
    short8 bq0, bq1, bqn0, bqn1;
    bqn0 = *(const short8*)(wp + boff);
    bqn1 = *(const short8*)(wp + boff + 512);

    // ---- stage A: closed-form uniform cubic B-spline bases -> bf16 LDS ----
    for (int u = t; u < 4 * 34 * CINC; u += 512) {    // 8704 items, 17 iters, x-innermost
        int x34 = u % 34;
        int rc = u / 34;
        int cl = rc & 63;
        int r = rc >> 6;
        int y = h0 + r;
        float v = 0.0f;
        if (y >= 1 && y <= HH && x34 >= 1 && x34 <= WW)
            v = xin[((b * CINC + cl) * HH + (y - 1)) * WW + (x34 - 1)];
        float sv = fmaf(v, 2.5f, 5.5f);               // (v + 2.2) / 0.4
        float cf = floorf(sv);
        int c = (int)cf;
        float f = sv - cf;
        float f2 = f * f, f3 = f2 * f;
        float omf = 1.0f - f;
        float w0 = f3 * (1.0f / 6.0f);
        float w1 = (1.0f + 3.0f * f + 3.0f * f2 - 3.0f * f3) * (1.0f / 6.0f);
        float w2 = (4.0f - 6.0f * f2 + 3.0f * f3) * (1.0f / 6.0f);
        float w3 = (omf * omf * omf) * (1.0f / 6.0f);
        short o8[8];
#pragma unroll
        for (int j = 0; j < 8; ++j) {
            float bj = (j == c) ? w0 : (j == c - 1) ? w1 : (j == c - 2) ? w2
                       : (j == c - 3) ? w3 : 0.0f;
            o8[j] = (short)f2bf(bj);
        }
        *(int4*)&A[(r * 34 + x34) * 512 + ((cl ^ (x34 & 15)) * 8)] = *(const int4*)o8;
    }
    __syncthreads();

    floatx4 acc0 = (floatx4)0.f, acc1 = (floatx4)0.f;

    // ---- main loop: 144 steps = 9 taps x 16 k-sixteenths, 1-step B prefetch ----
    // Last prefetch overruns into the 4 KB slack slot after W3 (never consumed).
    for (int tap = 0; tap < 9; ++tap) {
        const int kh = tap / 3, kw = tap % 3;
        const int x15 = (l15 + kw) & 15;              // xh is mult of 16 -> drops out
        const int arow = ((rowl + kh) * 34 + xh + l15 + kw) * 512;
#pragma unroll
        for (int s = 0; s < 16; ++s) {
            bq0 = bqn0; bq1 = bqn1;
            wp += 2048;
            bqn0 = *(const short8*)(wp + boff);
            bqn1 = *(const short8*)(wp + boff + 512);
            short8 aF = *(const short8*)&A[arow + (((s * 4 + q) ^ x15) * 8)];
            acc0 = __builtin_amdgcn_mfma_f32_16x16x32_bf16(aF, bq0, acc0, 0, 0, 0);
            acc1 = __builtin_amdgcn_mfma_f32_16x16x32_bf16(aF, bq1, acc1, 0, 0, 0);
        }
    }

    // ---- epilogue: direct float4 stores to out ----
    const int h = h0 + rowl;
    {
        const int oc0 = n0 + l15;
        float* op0 = out + (((size_t)b * COUT + oc0) * HH + h) * WW + xh + q * 4;
        *(floatx4*)op0 = acc0;
        const int oc1 = n0 + 16 + l15;
        float* op1 = out + (((size_t)b * COUT + oc1) * HH + h) * WW + xh + q * 4;
        *(floatx4*)op1 = acc1;
    }
}

extern "C" void kernel_launch(void* const* d_in, const int* in_sizes, int n_in,
                              void* d_out, int out_size, void* d_ws, size_t ws_size,
                              hipStream_t stream) {
    const float* x  = (const float*)d_in[0];
    const float* sw = (const float*)d_in[1];
    const float* sc = (const float*)d_in[2];
    float* out = (float*)d_out;
    short* W3 = (short*)d_ws;   // 294,912 bf16 = 576 KB (+4 KB prefetch slack)

    wt_kernel<<<(294912 + 255) / 256, 256, 0, stream>>>(sw, sc, W3);
    conv_kernel<<<256, 512, 0, stream>>>(x, W3, out);
}